// Round 10
// baseline (433.628 us; speedup 1.0000x reference)
//
#include <hip/hip_runtime.h>
#include <stdint.h>

#define IN_SIZE 224
#define KER 5
#define IN_CH 16
#define OUT_CH 64
#define NH 220
#define NB_TILES (NH * NH)       // 48400
#define XCH (IN_SIZE * IN_SIZE)  // 50176
#define OUT_PLANE NB_TILES
#define KP2 51200                // padded K for gemm: 64 chunks x 800
#define XS 52224                 // per-plane stride in shifted-x copies
#define XTROWS 50304             // xT rows (XCH + pad for tap overhang)
#define LR_OVER_NB ((float)(0.005 / 48400.0))
#define GAMMA_F 0.99f
#define ONE_MINUS_GAMMA 0.01f
#define EPS_F 0.01f

#define NCHUNK 64
#define CK 800
#define PSTRIDE (64 * 512)

typedef __attribute__((ext_vector_type(8))) short short8;
typedef __attribute__((ext_vector_type(4))) float floatx4;

__device__ inline uint16_t f2bf(float f) {
    uint32_t u = __float_as_uint(f);
    return (uint16_t)((u + 0x7FFFu + ((u >> 16) & 1u)) >> 16);
}
__device__ inline float bf2f(uint16_t h) { return __uint_as_float((uint32_t)h << 16); }

// ---- Kernel 0: 5 kj-shifted bf16 copies of x (gemm B); zero yb pads; zero colsum ----
__global__ __launch_bounds__(256) void xcast_kernel(const float* __restrict__ x,
                                                    uint16_t* __restrict__ xs,
                                                    uint16_t* __restrict__ yb,
                                                    float* __restrict__ colsum) {
    int t = blockIdx.x * 256 + threadIdx.x;
    const int perq = XS / 4;  // 13056
    if (t < 5 * 16 * perq) {
        int kj = t / (16 * perq);
        int rem = t - kj * (16 * perq);
        int c = rem / perq;
        int q = (rem - c * perq) * 4;
        int base = c * XCH;
        ushort4 o;
        int i0 = q + kj;     o.x = f2bf(x[base + (i0 < XCH ? i0 : XCH - 1)]);
        int i1 = q + kj + 1; o.y = f2bf(x[base + (i1 < XCH ? i1 : XCH - 1)]);
        int i2 = q + kj + 2; o.z = f2bf(x[base + (i2 < XCH ? i2 : XCH - 1)]);
        int i3 = q + kj + 3; o.w = f2bf(x[base + (i3 < XCH ? i3 : XCH - 1)]);
        *(ushort4*)(xs + (kj * 16 + c) * XS + q) = o;
    }
    ushort4 z = {0, 0, 0, 0};
    if (t < 64 * 480) {  // zero yb K-tail [49280,51200)
        int r = t / 480, q = (t - r * 480) * 4;
        *(ushort4*)(yb + r * KP2 + 49280 + q) = z;
    }
    if (t < 64 * 220) {  // zero yb j-pad cols 220..223
        int o = t / 220, i = t - o * 220;
        *(ushort4*)(yb + o * KP2 + i * 224 + 220) = z;
    }
    if (t < OUT_CH) colsum[t] = 0.f;
}

// ---- Kernel 0b: xT[pixel][channel] hi/lo bf16 + W tap-pair repack hi/lo (fused) ----
__global__ __launch_bounds__(256) void prep_kernel(const float* __restrict__ x,
                                                   uint16_t* __restrict__ xth,
                                                   uint16_t* __restrict__ xtl,
                                                   const float* __restrict__ W,
                                                   uint16_t* __restrict__ wrh,
                                                   uint16_t* __restrict__ wrl) {
    int b = blockIdx.x;
    if (b < 197) {  // xT part
        int addr = b * 256 + threadIdx.x;
        if (addr >= XTROWS) return;
        uint32_t dh[8], dl[8];
        if (addr < XCH) {
#pragma unroll
            for (int q = 0; q < 8; q++) {
                float v0 = x[(2 * q) * XCH + addr];
                float v1 = x[(2 * q + 1) * XCH + addr];
                uint16_t h0 = f2bf(v0), h1 = f2bf(v1);
                uint16_t l0 = f2bf(v0 - bf2f(h0)), l1 = f2bf(v1 - bf2f(h1));
                dh[q] = (uint32_t)h0 | ((uint32_t)h1 << 16);
                dl[q] = (uint32_t)l0 | ((uint32_t)l1 << 16);
            }
        } else {
#pragma unroll
            for (int q = 0; q < 8; q++) { dh[q] = 0u; dl[q] = 0u; }
        }
        *(uint4*)(xth + addr * 16) = make_uint4(dh[0], dh[1], dh[2], dh[3]);
        *(uint4*)(xth + addr * 16 + 8) = make_uint4(dh[4], dh[5], dh[6], dh[7]);
        *(uint4*)(xtl + addr * 16) = make_uint4(dl[0], dl[1], dl[2], dl[3]);
        *(uint4*)(xtl + addr * 16 + 8) = make_uint4(dl[4], dl[5], dl[6], dl[7]);
    } else {  // W repack: Wrep[t][oc][k], k = s*16 + c, tap = 2t+s
        int idx = (b - 197) * 256 + threadIdx.x;
        if (idx >= 13 * 2048) return;
        int t = idx >> 11;
        int rem = idx & 2047;
        int oc = rem >> 5;
        int k = rem & 31;
        int s = k >> 4, c = k & 15;
        int tap = 2 * t + s;
        float v = (tap < 25) ? W[oc * 400 + c * 25 + tap] : 0.f;
        uint16_t h = f2bf(v);
        wrh[idx] = h;
        wrl[idx] = f2bf(v - bf2f(h));
    }
}

// ---- Kernel 1: conv MFMA + wave-local inhibition + y emit + colsum ----
// Each wave: 16 positions (n) x all 64 oc (m). B private per wave; A L1-broadcast.
__global__ __launch_bounds__(256) void conv_inhib_kernel(const uint16_t* __restrict__ xth,
                                                         const uint16_t* __restrict__ xtl,
                                                         const uint16_t* __restrict__ wrh,
                                                         const uint16_t* __restrict__ wrl,
                                                         float* __restrict__ out,
                                                         uint16_t* __restrict__ yb,
                                                         float* __restrict__ colsum) {
    const int lane = threadIdx.x & 63;
    const int wid = threadIdx.x >> 6;  // position-group within block
    const int l15 = lane & 15;
    const int quad = lane >> 4;
    const int c0 = (quad & 1) * 8;
    const int sq = quad >> 1;
    const int P = blockIdx.x * 64 + wid * 16 + l15;

    floatx4 acc[4];
#pragma unroll
    for (int g = 0; g < 4; g++) acc[g] = (floatx4){0.f, 0.f, 0.f, 0.f};

    const uint16_t* bb_h = xth + P * 16 + c0;
    const uint16_t* bb_l = xtl + P * 16 + c0;
    const uint16_t* ab_h = wrh + l15 * 32 + quad * 8;  // + t*2048 + g*512
    const uint16_t* ab_l = wrl + l15 * 32 + quad * 8;

#pragma unroll
    for (int t = 0; t < 13; t++) {
        const int tap0 = 2 * t, tap1 = 2 * t + 1;
        const int o0 = (tap0 / 5) * 224 + (tap0 % 5);
        const int o1 = (tap1 <= 24) ? (tap1 / 5) * 224 + (tap1 % 5) : 0;
        const int off = sq ? o1 : o0;
        short8 bh = *(const short8*)(bb_h + off * 16);
        short8 bl = *(const short8*)(bb_l + off * 16);
#pragma unroll
        for (int g = 0; g < 4; g++) {
            short8 ah = *(const short8*)(ab_h + t * 2048 + g * 512);
            short8 al = *(const short8*)(ab_l + t * 2048 + g * 512);
            acc[g] = __builtin_amdgcn_mfma_f32_16x16x32_bf16(ah, bh, acc[g], 0, 0, 0);
            acc[g] = __builtin_amdgcn_mfma_f32_16x16x32_bf16(ah, bl, acc[g], 0, 0, 0);
            acc[g] = __builtin_amdgcn_mfma_f32_16x16x32_bf16(al, bh, acc[g], 0, 0, 0);
        }
    }

    // ---- wave-local inhibition epilogue (position = l15 column, all 64 oc in wave) ----
    const int i = P / 224;
    const int j = P - i * 224;
    const bool valid = j < NH;

    float mx = 0.f;
#pragma unroll
    for (int g = 0; g < 4; g++)
#pragma unroll
        for (int r = 0; r < 4; r++) mx = fmaxf(mx, acc[g][r]);
    mx = fmaxf(mx, __shfl_xor(mx, 16));  // combine quads (same l15/position)
    mx = fmaxf(mx, __shfl_xor(mx, 32));
    const float inv = 1.f / (mx + 1e-9f);

    float cs[16];
#pragma unroll
    for (int g = 0; g < 4; g++) {
#pragma unroll
        for (int r = 0; r < 4; r++) {
            float tv = fmaxf(acc[g][r], 0.f) * inv;
            float t2 = tv * tv;
            tv = t2 * t2 * tv;
            if (valid) {
                int oc = 16 * g + quad * 4 + r;
                out[oc * OUT_PLANE + i * NH + j] = tv;
                yb[oc * KP2 + P] = f2bf(tv);
            }
            cs[g * 4 + r] = valid ? tv : 0.f;
        }
    }
    // colsum: reduce over the 16 positions (l15) in each quad, atomic per oc
#pragma unroll
    for (int g = 0; g < 4; g++) {
#pragma unroll
        for (int r = 0; r < 4; r++) {
            float s = cs[g * 4 + r];
            s += __shfl_xor(s, 1);
            s += __shfl_xor(s, 2);
            s += __shfl_xor(s, 4);
            s += __shfl_xor(s, 8);
            if (l15 == 0) atomicAdd(colsum + 16 * g + quad * 4 + r, s);
        }
    }
}

// ---- Kernel 3: LDS-staged GEMM y^T(64xK) @ [xf|y](Kx464), XCD-swizzled grid ----
__global__ __launch_bounds__(256) void gemm_kernel(const uint16_t* __restrict__ yb,
                                                   const uint16_t* __restrict__ xs,
                                                   float* __restrict__ Mpart) {
    __shared__ uint16_t As[2][64 * 40];
    __shared__ uint16_t Bs[2][64 * 40];
    const int tid = threadIdx.x;
    const int lane = tid & 63;
    const int w = tid >> 6;
    const int l15 = lane & 15;
    const int quad = lane >> 4;
    const int kg = quad * 8;
    const int b = blockIdx.x;
    const int xcd = b & 7;
    const int t8 = b >> 3;
    const int ntile = t8 & 7;
    const int chunk = xcd + 8 * (t8 >> 3);
    const int k0 = chunk * CK;

    const int sr = tid >> 2;
    const int sseg = (tid & 3) * 8;
    const uint16_t* pa = yb + sr * KP2 + k0 + sseg;

    int n_g = ntile * 64 + sr;
    const uint16_t* pbase;
    if (n_g < 400) {
        int c = n_g / 25;
        int r = n_g - 25 * c;
        int ki = r / 5;
        int kj = r - 5 * ki;
        pbase = xs + (kj * 16 + c) * XS + ki * 224;
    } else if (n_g < 464) {
        pbase = yb + (n_g - 400) * KP2;
    } else {
        pbase = yb;
    }
    const uint16_t* pb = pbase + k0 + sseg;

    floatx4 acc[4];
#pragma unroll
    for (int i = 0; i < 4; i++) acc[i] = (floatx4){0.f, 0.f, 0.f, 0.f};

    uint4 ra = *(const uint4*)pa;
    uint4 rb = *(const uint4*)pb;

    for (int s = 0; s < 25; s++) {
        const int p = s & 1;
        *(uint4*)&As[p][sr * 40 + sseg] = ra;
        *(uint4*)&Bs[p][sr * 40 + sseg] = rb;
        __syncthreads();
        if (s + 1 < 25) {
            pa += 32;
            pb += 32;
            ra = *(const uint4*)pa;
            rb = *(const uint4*)pb;
        }
        short8 af = *(const short8*)&As[p][(16 * w + l15) * 40 + kg];
#pragma unroll
        for (int ng = 0; ng < 4; ng++) {
            short8 bf = *(const short8*)&Bs[p][(16 * ng + l15) * 40 + kg];
            acc[ng] = __builtin_amdgcn_mfma_f32_16x16x32_bf16(af, bf, acc[ng], 0, 0, 0);
        }
        __syncthreads();
    }

    float* dst = Mpart + chunk * PSTRIDE;
#pragma unroll
    for (int ng = 0; ng < 4; ng++) {
        int col = ntile * 64 + ng * 16 + l15;
        if (col < 464) {
#pragma unroll
            for (int r = 0; r < 4; r++)
                dst[(16 * w + quad * 4 + r) * 512 + col] = acc[ng][r];
        }
    }
}

// ---- Kernel 4: reduce partials -> M (64x400) and yty (64x64) ----
__global__ __launch_bounds__(256) void reduce_kernel(const float* __restrict__ Mpart,
                                                     float* __restrict__ M,
                                                     float* __restrict__ yty) {
    int e = blockIdx.x * 256 + threadIdx.x;
    float s = 0.f;
#pragma unroll 8
    for (int ch = 0; ch < NCHUNK; ch++) s += Mpart[ch * PSTRIDE + e];
    int row = e >> 9, col = e & 511;
    if (col < 400) M[row * 400 + col] = s;
    else if (col < 464) yty[row * 64 + (col - 400)] = s;
}

// ---- Kernel 5: Wfinal (+ fused exp_new/gfp) ----
__global__ __launch_bounds__(256) void finalize_w_kernel(const float* __restrict__ W,
                                                         const float* __restrict__ yty,
                                                         const float* __restrict__ M,
                                                         const float* __restrict__ colsum,
                                                         const float* __restrict__ exp_avg,
                                                         float* __restrict__ Wout,
                                                         float* __restrict__ expout) {
    __shared__ float gfps[OUT_CH];
    if (threadIdx.x < OUT_CH) {
        int o = threadIdx.x;
        float e = GAMMA_F * exp_avg[o] + ONE_MINUS_GAMMA * (colsum[o] / (float)NB_TILES);
        float s = e;
        for (int off = 32; off; off >>= 1) s += __shfl_down(s, off);
        s = __shfl(s, 0);
        float A = e / (s / (float)OUT_CH);
        gfps[o] = EPS_F * tanhf(-EPS_F * (A - 1.f)) + 1.f;
        if (blockIdx.x == 0) expout[o] = e;
    }
    __syncthreads();
    int idx = blockIdx.x * 256 + threadIdx.x;
    int o = idx / 400;
    int q = idx - o * 400;
    float dot = 0.f;
#pragma unroll 8
    for (int k = 0; k < OUT_CH; k++) dot = fmaf(yty[o * 64 + k], W[k * 400 + q], dot);
    float w = W[idx] + LR_OVER_NB * (M[idx] - dot);
    w = fmaxf(w, 0.f);
    float gp = gfps[o];
    float pos = (w > 0.f ? w : 0.f) * gp;
    float neg = (w < 0.f ? w : 0.f) / gp;
    Wout[idx] = pos + neg;
}

extern "C" void kernel_launch(void* const* d_in, const int* in_sizes, int n_in,
                              void* d_out, int out_size, void* d_ws, size_t ws_size,
                              hipStream_t stream) {
    const float* x = (const float*)d_in[0];
    const float* W = (const float*)d_in[1];
    const float* exp_avg = (const float*)d_in[2];
    float* out = (float*)d_out;

    float* wsf = (float*)d_ws;
    float* colsum = wsf;                        // 64
    float* M = wsf + 64;                        // 25600
    float* yty = wsf + 25664;                   // 4096 -> 29760
    float* Mpart = wsf + 29760;                 // 64*32768 floats
    // conv-side buffers overlaid on Mpart (dead until gemm writes it)
    uint16_t* xth = (uint16_t*)Mpart;           // 50304*16
    uint16_t* xtl = xth + XTROWS * 16;          // 50304*16
    uint16_t* wrh = xtl + XTROWS * 16;          // 26624
    uint16_t* wrl = wrh + 26624;                // 26624
    uint16_t* ybf = (uint16_t*)(wsf + 29760 + NCHUNK * PSTRIDE);  // 64*51200 bf16
    uint16_t* xsb = ybf + OUT_CH * KP2;                            // 5*16*52224 bf16

    float* Wout = out + OUT_CH * OUT_PLANE;
    float* expout = Wout + OUT_CH * IN_CH * KER * KER;

    xcast_kernel<<<4080, 256, 0, stream>>>(x, xsb, ybf, colsum);
    prep_kernel<<<301, 256, 0, stream>>>(x, xth, xtl, W, wrh, wrl);
    conv_inhib_kernel<<<770, 256, 0, stream>>>(xth, xtl, wrh, wrl, out, ybf, colsum);
    gemm_kernel<<<512, 256, 0, stream>>>(ybf, xsb, Mpart);
    reduce_kernel<<<128, 256, 0, stream>>>(Mpart, M, yty);
    finalize_w_kernel<<<100, 256, 0, stream>>>(W, yty, M, colsum, exp_avg, Wout, expout);
}

// Round 11
// 159.702 us; speedup vs baseline: 2.7152x; 2.7152x over previous
//
#include <hip/hip_runtime.h>
#include <stdint.h>

#define IN_SIZE 224
#define KER 5
#define IN_CH 16
#define OUT_CH 64
#define NH 220
#define NB_TILES (NH * NH)       // 48400
#define XCH (IN_SIZE * IN_SIZE)  // 50176
#define OUT_PLANE NB_TILES
#define KP2 51200                // padded K for gemm: 64 chunks x 800
#define XS 52224                 // per-plane stride in shifted-x copies
#define XTROWS 50304             // xT rows (XCH + pad for tap overhang)
#define LR_OVER_NB ((float)(0.005 / 48400.0))
#define GAMMA_F 0.99f
#define ONE_MINUS_GAMMA 0.01f
#define EPS_F 0.01f

#define NCHUNK 64
#define CK 800
#define PSTRIDE (64 * 512)

typedef __attribute__((ext_vector_type(8))) short short8;
typedef __attribute__((ext_vector_type(4))) float floatx4;

__device__ inline uint16_t f2bf(float f) {
    uint32_t u = __float_as_uint(f);
    return (uint16_t)((u + 0x7FFFu + ((u >> 16) & 1u)) >> 16);
}
__device__ inline float bf2f(uint16_t h) { return __uint_as_float((uint32_t)h << 16); }

// ---- Kernel 0: 5 kj-shifted bf16 copies of x (gemm B); zero yb pads; zero colsum ----
__global__ __launch_bounds__(256) void xcast_kernel(const float* __restrict__ x,
                                                    uint16_t* __restrict__ xs,
                                                    uint16_t* __restrict__ yb,
                                                    float* __restrict__ colsum) {
    int t = blockIdx.x * 256 + threadIdx.x;
    const int perq = XS / 4;  // 13056
    if (t < 5 * 16 * perq) {
        int kj = t / (16 * perq);
        int rem = t - kj * (16 * perq);
        int c = rem / perq;
        int q = (rem - c * perq) * 4;
        int base = c * XCH;
        ushort4 o;
        int i0 = q + kj;     o.x = f2bf(x[base + (i0 < XCH ? i0 : XCH - 1)]);
        int i1 = q + kj + 1; o.y = f2bf(x[base + (i1 < XCH ? i1 : XCH - 1)]);
        int i2 = q + kj + 2; o.z = f2bf(x[base + (i2 < XCH ? i2 : XCH - 1)]);
        int i3 = q + kj + 3; o.w = f2bf(x[base + (i3 < XCH ? i3 : XCH - 1)]);
        *(ushort4*)(xs + (kj * 16 + c) * XS + q) = o;
    }
    ushort4 z = {0, 0, 0, 0};
    if (t < 64 * 480) {  // zero yb K-tail [49280,51200)
        int r = t / 480, q = (t - r * 480) * 4;
        *(ushort4*)(yb + r * KP2 + 49280 + q) = z;
    }
    if (t < 64 * 220) {  // zero yb j-pad cols 220..223
        int o = t / 220, i = t - o * 220;
        *(ushort4*)(yb + o * KP2 + i * 224 + 220) = z;
    }
    if (t < OUT_CH) colsum[t] = 0.f;
}

// ---- Kernel 0b: xT hi/lo + W fragment-packed repack (lane-major, coalesced A loads) ----
// wrp[t][ocg][lane][j] = W(oc=16*ocg+(lane&15), k=(lane>>4)*8+j, tap=2t+(k>>4))
__global__ __launch_bounds__(256) void prep_kernel(const float* __restrict__ x,
                                                   uint16_t* __restrict__ xth,
                                                   uint16_t* __restrict__ xtl,
                                                   const float* __restrict__ W,
                                                   uint16_t* __restrict__ wrh,
                                                   uint16_t* __restrict__ wrl) {
    int b = blockIdx.x;
    if (b < 197) {  // xT part
        int addr = b * 256 + threadIdx.x;
        if (addr >= XTROWS) return;
        uint32_t dh[8], dl[8];
        if (addr < XCH) {
#pragma unroll
            for (int q = 0; q < 8; q++) {
                float v0 = x[(2 * q) * XCH + addr];
                float v1 = x[(2 * q + 1) * XCH + addr];
                uint16_t h0 = f2bf(v0), h1 = f2bf(v1);
                uint16_t l0 = f2bf(v0 - bf2f(h0)), l1 = f2bf(v1 - bf2f(h1));
                dh[q] = (uint32_t)h0 | ((uint32_t)h1 << 16);
                dl[q] = (uint32_t)l0 | ((uint32_t)l1 << 16);
            }
        } else {
#pragma unroll
            for (int q = 0; q < 8; q++) { dh[q] = 0u; dl[q] = 0u; }
        }
        *(uint4*)(xth + addr * 16) = make_uint4(dh[0], dh[1], dh[2], dh[3]);
        *(uint4*)(xth + addr * 16 + 8) = make_uint4(dh[4], dh[5], dh[6], dh[7]);
        *(uint4*)(xtl + addr * 16) = make_uint4(dl[0], dl[1], dl[2], dl[3]);
        *(uint4*)(xtl + addr * 16 + 8) = make_uint4(dl[4], dl[5], dl[6], dl[7]);
    } else {  // W fragment-packed repack
        int idx = (b - 197) * 256 + threadIdx.x;
        if (idx >= 13 * 4 * 64 * 8) return;
        int j = idx & 7;
        int lane = (idx >> 3) & 63;
        int ocg = (idx >> 9) & 3;
        int t = idx >> 11;
        int k = (lane >> 4) * 8 + j;
        int s = k >> 4, c = k & 15;
        int oc = 16 * ocg + (lane & 15);
        int tap = 2 * t + s;
        float v = (tap < 25) ? W[oc * 400 + c * 25 + tap] : 0.f;
        uint16_t h = f2bf(v);
        wrh[idx] = h;
        wrl[idx] = f2bf(v - bf2f(h));
    }
}

// ---- Kernel 1: conv via MFMA (wave = 16 oc x 64 positions, all loads coalesced) ----
__global__ __launch_bounds__(256) void conv_mfma_kernel(const uint16_t* __restrict__ xth,
                                                        const uint16_t* __restrict__ xtl,
                                                        const uint16_t* __restrict__ wrh,
                                                        const uint16_t* __restrict__ wrl,
                                                        float* __restrict__ out) {
    const int lane = threadIdx.x & 63;
    const int w = threadIdx.x >> 6;   // oc-group: rows 16w..16w+15
    const int l15 = lane & 15;
    const int quad = lane >> 4;
    const int P0 = blockIdx.x * 64;
    const int c0 = (quad & 1) * 8;
    const int sq = quad >> 1;

    floatx4 acc[4];
#pragma unroll
    for (int g = 0; g < 4; g++) acc[g] = (floatx4){0.f, 0.f, 0.f, 0.f};

#pragma unroll
    for (int t = 0; t < 13; t++) {
        // A fragments: lane-major packed -> one contiguous 1KB load per instruction
        short8 ah = *(const short8*)(wrh + ((t * 4 + w) * 64 + lane) * 8);
        short8 al = *(const short8*)(wrl + ((t * 4 + w) * 64 + lane) * 8);
        const int tap0 = 2 * t, tap1 = 2 * t + 1;
        const int o0 = (tap0 / 5) * 224 + (tap0 % 5);
        const int o1 = (tap1 <= 24) ? (tap1 / 5) * 224 + (tap1 % 5) : 0;
        const int off = sq ? o1 : o0;
#pragma unroll
        for (int g = 0; g < 4; g++) {
            int P = P0 + 16 * g + l15;
            short8 bh = *(const short8*)(xth + (P + off) * 16 + c0);
            short8 bl = *(const short8*)(xtl + (P + off) * 16 + c0);
            acc[g] = __builtin_amdgcn_mfma_f32_16x16x32_bf16(ah, bh, acc[g], 0, 0, 0);
            acc[g] = __builtin_amdgcn_mfma_f32_16x16x32_bf16(ah, bl, acc[g], 0, 0, 0);
            acc[g] = __builtin_amdgcn_mfma_f32_16x16x32_bf16(al, bh, acc[g], 0, 0, 0);
        }
    }

#pragma unroll
    for (int g = 0; g < 4; g++) {
        int P = P0 + 16 * g + l15;
        int i = P / 224;
        int j = P - i * 224;
        if (j < NH) {
            float* o = out + i * NH + j;
#pragma unroll
            for (int r = 0; r < 4; r++)
                o[(16 * w + quad * 4 + r) * OUT_PLANE] = acc[g][r];
        }
    }
}

// ---- Kernel 2: inhibition (fp32 in-place) + bf16 y copy + fused colsum ----
__global__ __launch_bounds__(128) void inhib_kernel(float* __restrict__ out,
                                                    uint16_t* __restrict__ yb,
                                                    float* __restrict__ colsum) {
    int p = blockIdx.x * 128 + threadIdx.x;
    bool valid = p < NB_TILES;
    int pc = valid ? p : 0;
    int i = pc / NH;
    int j = pc - i * NH;
    float v[OUT_CH];
    float m = 0.f;
#pragma unroll
    for (int oc = 0; oc < OUT_CH; oc++) {
        float t = valid ? out[oc * OUT_PLANE + p] : 0.f;
        t = fmaxf(t, 0.f);
        v[oc] = t;
        m = fmaxf(m, t);
    }
    float inv = 1.f / (m + 1e-9f);
    __shared__ float sm[OUT_CH * 2];
    const int lane = threadIdx.x & 63, wv = threadIdx.x >> 6;
#pragma unroll
    for (int oc = 0; oc < OUT_CH; oc++) {
        float t = v[oc] * inv;
        float t2 = t * t;
        t = t2 * t2 * t;
        if (valid) {
            out[oc * OUT_PLANE + p] = t;
            yb[oc * KP2 + i * 224 + j] = f2bf(t);
        }
        float r = t;
        for (int off = 32; off; off >>= 1) r += __shfl_down(r, off);
        if (lane == 0) sm[oc * 2 + wv] = r;
    }
    __syncthreads();
    if (threadIdx.x < OUT_CH) {
        int oc = threadIdx.x;
        atomicAdd(colsum + oc, sm[oc * 2] + sm[oc * 2 + 1]);
    }
}

// ---- Kernel 3: LDS-staged GEMM y^T(64xK) @ [xf|y](Kx464), XCD-swizzled grid ----
__global__ __launch_bounds__(256) void gemm_kernel(const uint16_t* __restrict__ yb,
                                                   const uint16_t* __restrict__ xs,
                                                   float* __restrict__ Mpart) {
    __shared__ uint16_t As[2][64 * 40];
    __shared__ uint16_t Bs[2][64 * 40];
    const int tid = threadIdx.x;
    const int lane = tid & 63;
    const int w = tid >> 6;
    const int l15 = lane & 15;
    const int quad = lane >> 4;
    const int kg = quad * 8;
    const int b = blockIdx.x;
    const int xcd = b & 7;
    const int t8 = b >> 3;
    const int ntile = t8 & 7;
    const int chunk = xcd + 8 * (t8 >> 3);
    const int k0 = chunk * CK;

    const int sr = tid >> 2;
    const int sseg = (tid & 3) * 8;
    const uint16_t* pa = yb + sr * KP2 + k0 + sseg;

    int n_g = ntile * 64 + sr;
    const uint16_t* pbase;
    if (n_g < 400) {
        int c = n_g / 25;
        int r = n_g - 25 * c;
        int ki = r / 5;
        int kj = r - 5 * ki;
        pbase = xs + (kj * 16 + c) * XS + ki * 224;
    } else if (n_g < 464) {
        pbase = yb + (n_g - 400) * KP2;
    } else {
        pbase = yb;
    }
    const uint16_t* pb = pbase + k0 + sseg;

    floatx4 acc[4];
#pragma unroll
    for (int i = 0; i < 4; i++) acc[i] = (floatx4){0.f, 0.f, 0.f, 0.f};

    uint4 ra = *(const uint4*)pa;
    uint4 rb = *(const uint4*)pb;

    for (int s = 0; s < 25; s++) {
        const int p = s & 1;
        *(uint4*)&As[p][sr * 40 + sseg] = ra;
        *(uint4*)&Bs[p][sr * 40 + sseg] = rb;
        __syncthreads();
        if (s + 1 < 25) {
            pa += 32;
            pb += 32;
            ra = *(const uint4*)pa;
            rb = *(const uint4*)pb;
        }
        short8 af = *(const short8*)&As[p][(16 * w + l15) * 40 + kg];
#pragma unroll
        for (int ng = 0; ng < 4; ng++) {
            short8 bf = *(const short8*)&Bs[p][(16 * ng + l15) * 40 + kg];
            acc[ng] = __builtin_amdgcn_mfma_f32_16x16x32_bf16(af, bf, acc[ng], 0, 0, 0);
        }
        __syncthreads();
    }

    float* dst = Mpart + chunk * PSTRIDE;
#pragma unroll
    for (int ng = 0; ng < 4; ng++) {
        int col = ntile * 64 + ng * 16 + l15;
        if (col < 464) {
#pragma unroll
            for (int r = 0; r < 4; r++)
                dst[(16 * w + quad * 4 + r) * 512 + col] = acc[ng][r];
        }
    }
}

// ---- Kernel 4: reduce partials -> M (64x400) and yty (64x64) ----
__global__ __launch_bounds__(256) void reduce_kernel(const float* __restrict__ Mpart,
                                                     float* __restrict__ M,
                                                     float* __restrict__ yty) {
    int e = blockIdx.x * 256 + threadIdx.x;
    float s = 0.f;
#pragma unroll 8
    for (int ch = 0; ch < NCHUNK; ch++) s += Mpart[ch * PSTRIDE + e];
    int row = e >> 9, col = e & 511;
    if (col < 400) M[row * 400 + col] = s;
    else if (col < 464) yty[row * 64 + (col - 400)] = s;
}

// ---- Kernel 5: Wfinal (+ fused exp_new/gfp) ----
__global__ __launch_bounds__(256) void finalize_w_kernel(const float* __restrict__ W,
                                                         const float* __restrict__ yty,
                                                         const float* __restrict__ M,
                                                         const float* __restrict__ colsum,
                                                         const float* __restrict__ exp_avg,
                                                         float* __restrict__ Wout,
                                                         float* __restrict__ expout) {
    __shared__ float gfps[OUT_CH];
    if (threadIdx.x < OUT_CH) {
        int o = threadIdx.x;
        float e = GAMMA_F * exp_avg[o] + ONE_MINUS_GAMMA * (colsum[o] / (float)NB_TILES);
        float s = e;
        for (int off = 32; off; off >>= 1) s += __shfl_down(s, off);
        s = __shfl(s, 0);
        float A = e / (s / (float)OUT_CH);
        gfps[o] = EPS_F * tanhf(-EPS_F * (A - 1.f)) + 1.f;
        if (blockIdx.x == 0) expout[o] = e;
    }
    __syncthreads();
    int idx = blockIdx.x * 256 + threadIdx.x;
    int o = idx / 400;
    int q = idx - o * 400;
    float dot = 0.f;
#pragma unroll 8
    for (int k = 0; k < OUT_CH; k++) dot = fmaf(yty[o * 64 + k], W[k * 400 + q], dot);
    float w = W[idx] + LR_OVER_NB * (M[idx] - dot);
    w = fmaxf(w, 0.f);
    float gp = gfps[o];
    float pos = (w > 0.f ? w : 0.f) * gp;
    float neg = (w < 0.f ? w : 0.f) / gp;
    Wout[idx] = pos + neg;
}

extern "C" void kernel_launch(void* const* d_in, const int* in_sizes, int n_in,
                              void* d_out, int out_size, void* d_ws, size_t ws_size,
                              hipStream_t stream) {
    const float* x = (const float*)d_in[0];
    const float* W = (const float*)d_in[1];
    const float* exp_avg = (const float*)d_in[2];
    float* out = (float*)d_out;

    float* wsf = (float*)d_ws;
    float* colsum = wsf;                        // 64
    float* M = wsf + 64;                        // 25600
    float* yty = wsf + 25664;                   // 4096 -> 29760
    float* Mpart = wsf + 29760;                 // 64*32768 floats
    // conv-side buffers overlaid on Mpart (dead until gemm writes it)
    uint16_t* xth = (uint16_t*)Mpart;           // 50304*16
    uint16_t* xtl = xth + XTROWS * 16;          // 50304*16
    uint16_t* wrh = xtl + XTROWS * 16;          // 26624
    uint16_t* wrl = wrh + 26624;                // 26624
    uint16_t* ybf = (uint16_t*)(wsf + 29760 + NCHUNK * PSTRIDE);  // 64*51200 bf16
    uint16_t* xsb = ybf + OUT_CH * KP2;                            // 5*16*52224 bf16

    float* Wout = out + OUT_CH * OUT_PLANE;
    float* expout = Wout + OUT_CH * IN_CH * KER * KER;

    xcast_kernel<<<4080, 256, 0, stream>>>(x, xsb, ybf, colsum);
    prep_kernel<<<301, 256, 0, stream>>>(x, xth, xtl, W, wrh, wrl);
    conv_mfma_kernel<<<770, 256, 0, stream>>>(xth, xtl, wrh, wrl, out);
    inhib_kernel<<<(NB_TILES + 127) / 128, 128, 0, stream>>>(out, ybf, colsum);
    gemm_kernel<<<512, 256, 0, stream>>>(ybf, xsb, Mpart);
    reduce_kernel<<<128, 256, 0, stream>>>(Mpart, M, yty);
    finalize_w_kernel<<<100, 256, 0, stream>>>(W, yty, M, colsum, exp_avg, Wout, expout);
}

// Round 12
// 119.295 us; speedup vs baseline: 3.6349x; 1.3387x over previous
//
#include <hip/hip_runtime.h>
#include <stdint.h>

#define IN_SIZE 224
#define KER 5
#define IN_CH 16
#define OUT_CH 64
#define NH 220
#define NB_TILES (NH * NH)       // 48400
#define XCH (IN_SIZE * IN_SIZE)  // 50176
#define OUT_PLANE NB_TILES
#define KP2 51200                // padded K for gemm: 64 chunks x 800
#define XS 52224                 // per-plane stride in shifted-x copies
#define XTROWS 50304             // xT rows (XCH + pad for tap overhang)
#define LR_OVER_NB ((float)(0.005 / 48400.0))
#define GAMMA_F 0.99f
#define ONE_MINUS_GAMMA 0.01f
#define EPS_F 0.01f

#define NCHUNK 64
#define CK 800
#define PSTRIDE (64 * 512)

typedef __attribute__((ext_vector_type(8))) short short8;
typedef __attribute__((ext_vector_type(4))) float floatx4;

__device__ inline uint16_t f2bf(float f) {
    uint32_t u = __float_as_uint(f);
    return (uint16_t)((u + 0x7FFFu + ((u >> 16) & 1u)) >> 16);
}
__device__ inline float bf2f(uint16_t h) { return __uint_as_float((uint32_t)h << 16); }

// ---- Kernel 0: 5 kj-shifted bf16 x copies (gemm B); ones col; zero yb pads ----
__global__ __launch_bounds__(256) void xcast_kernel(const float* __restrict__ x,
                                                    uint16_t* __restrict__ xs,
                                                    uint16_t* __restrict__ yb,
                                                    uint16_t* __restrict__ ones) {
    int t = blockIdx.x * 256 + threadIdx.x;
    const int perq = XS / 4;  // 13056
    if (t < 5 * 16 * perq) {
        int kj = t / (16 * perq);
        int rem = t - kj * (16 * perq);
        int c = rem / perq;
        int q = (rem - c * perq) * 4;
        int base = c * XCH;
        ushort4 o;
        int i0 = q + kj;     o.x = f2bf(x[base + (i0 < XCH ? i0 : XCH - 1)]);
        int i1 = q + kj + 1; o.y = f2bf(x[base + (i1 < XCH ? i1 : XCH - 1)]);
        int i2 = q + kj + 2; o.z = f2bf(x[base + (i2 < XCH ? i2 : XCH - 1)]);
        int i3 = q + kj + 3; o.w = f2bf(x[base + (i3 < XCH ? i3 : XCH - 1)]);
        *(ushort4*)(xs + (kj * 16 + c) * XS + q) = o;
    }
    ushort4 z = {0, 0, 0, 0};
    if (t < 64 * 480) {  // zero yb K-tail [49280,51200)
        int r = t / 480, q = (t - r * 480) * 4;
        *(ushort4*)(yb + r * KP2 + 49280 + q) = z;
    }
    if (t < 64 * 220) {  // zero yb j-pad cols 220..223
        int o = t / 220, i = t - o * 220;
        *(ushort4*)(yb + o * KP2 + i * 224 + 220) = z;
    }
    if (t < 12816) {  // bf16 ones vector (51264 entries)
        ushort4 o1 = {0x3F80, 0x3F80, 0x3F80, 0x3F80};
        ((ushort4*)ones)[t] = o1;
    }
}

// ---- Kernel 0b: xT hi/lo + W fragment-packed repack (lane-major, coalesced A loads) ----
__global__ __launch_bounds__(256) void prep_kernel(const float* __restrict__ x,
                                                   uint16_t* __restrict__ xth,
                                                   uint16_t* __restrict__ xtl,
                                                   const float* __restrict__ W,
                                                   uint16_t* __restrict__ wrh,
                                                   uint16_t* __restrict__ wrl) {
    int b = blockIdx.x;
    if (b < 197) {  // xT part
        int addr = b * 256 + threadIdx.x;
        if (addr >= XTROWS) return;
        uint32_t dh[8], dl[8];
        if (addr < XCH) {
#pragma unroll
            for (int q = 0; q < 8; q++) {
                float v0 = x[(2 * q) * XCH + addr];
                float v1 = x[(2 * q + 1) * XCH + addr];
                uint16_t h0 = f2bf(v0), h1 = f2bf(v1);
                uint16_t l0 = f2bf(v0 - bf2f(h0)), l1 = f2bf(v1 - bf2f(h1));
                dh[q] = (uint32_t)h0 | ((uint32_t)h1 << 16);
                dl[q] = (uint32_t)l0 | ((uint32_t)l1 << 16);
            }
        } else {
#pragma unroll
            for (int q = 0; q < 8; q++) { dh[q] = 0u; dl[q] = 0u; }
        }
        *(uint4*)(xth + addr * 16) = make_uint4(dh[0], dh[1], dh[2], dh[3]);
        *(uint4*)(xth + addr * 16 + 8) = make_uint4(dh[4], dh[5], dh[6], dh[7]);
        *(uint4*)(xtl + addr * 16) = make_uint4(dl[0], dl[1], dl[2], dl[3]);
        *(uint4*)(xtl + addr * 16 + 8) = make_uint4(dl[4], dl[5], dl[6], dl[7]);
    } else {  // W fragment-packed: wrp[t][ocg][lane][j]
        int idx = (b - 197) * 256 + threadIdx.x;
        if (idx >= 13 * 4 * 64 * 8) return;
        int j = idx & 7;
        int lane = (idx >> 3) & 63;
        int ocg = (idx >> 9) & 3;
        int t = idx >> 11;
        int k = (lane >> 4) * 8 + j;
        int s = k >> 4, c = k & 15;
        int oc = 16 * ocg + (lane & 15);
        int tap = 2 * t + s;
        float v = (tap < 25) ? W[oc * 400 + c * 25 + tap] : 0.f;
        uint16_t h = f2bf(v);
        wrh[idx] = h;
        wrl[idx] = f2bf(v - bf2f(h));
    }
}

// ---- Kernel 1: conv MFMA (packed-A, coalesced) + FUSED inhibition epilogue ----
__global__ __launch_bounds__(256) void conv_inhib_kernel(const uint16_t* __restrict__ xth,
                                                         const uint16_t* __restrict__ xtl,
                                                         const uint16_t* __restrict__ wrh,
                                                         const uint16_t* __restrict__ wrl,
                                                         float* __restrict__ out,
                                                         uint16_t* __restrict__ yb) {
    const int lane = threadIdx.x & 63;
    const int w = threadIdx.x >> 6;   // oc-group: rows 16w..16w+15
    const int l15 = lane & 15;
    const int quad = lane >> 4;
    const int P0 = blockIdx.x * 64;
    const int c0 = (quad & 1) * 8;
    const int sq = quad >> 1;

    floatx4 acc[4];
#pragma unroll
    for (int g = 0; g < 4; g++) acc[g] = (floatx4){0.f, 0.f, 0.f, 0.f};

#pragma unroll
    for (int t = 0; t < 13; t++) {
        short8 ah = *(const short8*)(wrh + ((t * 4 + w) * 64 + lane) * 8);
        short8 al = *(const short8*)(wrl + ((t * 4 + w) * 64 + lane) * 8);
        const int tap0 = 2 * t, tap1 = 2 * t + 1;
        const int o0 = (tap0 / 5) * 224 + (tap0 % 5);
        const int o1 = (tap1 <= 24) ? (tap1 / 5) * 224 + (tap1 % 5) : 0;
        const int off = sq ? o1 : o0;
#pragma unroll
        for (int g = 0; g < 4; g++) {
            int P = P0 + 16 * g + l15;
            short8 bh = *(const short8*)(xth + (P + off) * 16 + c0);
            short8 bl = *(const short8*)(xtl + (P + off) * 16 + c0);
            acc[g] = __builtin_amdgcn_mfma_f32_16x16x32_bf16(ah, bh, acc[g], 0, 0, 0);
            acc[g] = __builtin_amdgcn_mfma_f32_16x16x32_bf16(ah, bl, acc[g], 0, 0, 0);
            acc[g] = __builtin_amdgcn_mfma_f32_16x16x32_bf16(al, bh, acc[g], 0, 0, 0);
        }
    }

    // ---- fused inhibition: channel-max across (r, quad) in-wave, across waves via LDS ----
    __shared__ float wmax[4][64];
    float pmax[4];
#pragma unroll
    for (int g = 0; g < 4; g++) {
        float mx = fmaxf(fmaxf(acc[g][0], acc[g][1]), fmaxf(acc[g][2], acc[g][3]));
        mx = fmaxf(mx, 0.f);
        mx = fmaxf(mx, __shfl_xor(mx, 16));  // combine quads (same position)
        mx = fmaxf(mx, __shfl_xor(mx, 32));
        pmax[g] = mx;
    }
    if (quad == 0) {
#pragma unroll
        for (int g = 0; g < 4; g++) wmax[w][g * 16 + l15] = pmax[g];
    }
    __syncthreads();

#pragma unroll
    for (int g = 0; g < 4; g++) {
        int P = P0 + 16 * g + l15;
        int i = P / 224;
        int j = P - i * 224;
        bool valid = j < NH;
        float mx = fmaxf(fmaxf(wmax[0][g * 16 + l15], wmax[1][g * 16 + l15]),
                         fmaxf(wmax[2][g * 16 + l15], wmax[3][g * 16 + l15]));
        float inv = 1.f / (mx + 1e-9f);
#pragma unroll
        for (int r = 0; r < 4; r++) {
            float tv = fmaxf(acc[g][r], 0.f) * inv;
            float t2 = tv * tv;
            tv = t2 * t2 * tv;
            if (valid) {
                int oc = 16 * w + quad * 4 + r;
                out[oc * OUT_PLANE + i * NH + j] = tv;
                yb[oc * KP2 + P] = f2bf(tv);
            }
        }
    }
}

// ---- Kernel 3: LDS-staged GEMM y^T(64xK) @ [xf|y|1](Kx465), XCD-swizzled grid ----
__global__ __launch_bounds__(256) void gemm_kernel(const uint16_t* __restrict__ yb,
                                                   const uint16_t* __restrict__ xs,
                                                   const uint16_t* __restrict__ ones,
                                                   float* __restrict__ Mpart) {
    __shared__ uint16_t As[2][64 * 40];
    __shared__ uint16_t Bs[2][64 * 40];
    const int tid = threadIdx.x;
    const int lane = tid & 63;
    const int w = tid >> 6;
    const int l15 = lane & 15;
    const int quad = lane >> 4;
    const int kg = quad * 8;
    const int b = blockIdx.x;
    const int xcd = b & 7;
    const int t8 = b >> 3;
    const int ntile = t8 & 7;
    const int chunk = xcd + 8 * (t8 >> 3);
    const int k0 = chunk * CK;

    const int sr = tid >> 2;
    const int sseg = (tid & 3) * 8;
    const uint16_t* pa = yb + sr * KP2 + k0 + sseg;

    int n_g = ntile * 64 + sr;
    const uint16_t* pbase;
    if (n_g < 400) {
        int c = n_g / 25;
        int r = n_g - 25 * c;
        int ki = r / 5;
        int kj = r - 5 * ki;
        pbase = xs + (kj * 16 + c) * XS + ki * 224;
    } else if (n_g < 464) {
        pbase = yb + (n_g - 400) * KP2;
    } else if (n_g == 464) {
        pbase = ones;
    } else {
        pbase = yb;  // dead column
    }
    const uint16_t* pb = pbase + k0 + sseg;

    floatx4 acc[4];
#pragma unroll
    for (int i = 0; i < 4; i++) acc[i] = (floatx4){0.f, 0.f, 0.f, 0.f};

    uint4 ra = *(const uint4*)pa;
    uint4 rb = *(const uint4*)pb;

    for (int s = 0; s < 25; s++) {
        const int p = s & 1;
        *(uint4*)&As[p][sr * 40 + sseg] = ra;
        *(uint4*)&Bs[p][sr * 40 + sseg] = rb;
        __syncthreads();
        if (s + 1 < 25) {
            pa += 32;
            pb += 32;
            ra = *(const uint4*)pa;
            rb = *(const uint4*)pb;
        }
        short8 af = *(const short8*)&As[p][(16 * w + l15) * 40 + kg];
#pragma unroll
        for (int ng = 0; ng < 4; ng++) {
            short8 bf = *(const short8*)&Bs[p][(16 * ng + l15) * 40 + kg];
            acc[ng] = __builtin_amdgcn_mfma_f32_16x16x32_bf16(af, bf, acc[ng], 0, 0, 0);
        }
        __syncthreads();
    }

    float* dst = Mpart + chunk * PSTRIDE;
#pragma unroll
    for (int ng = 0; ng < 4; ng++) {
        int col = ntile * 64 + ng * 16 + l15;
        if (col < 465) {
#pragma unroll
            for (int r = 0; r < 4; r++)
                dst[(16 * w + quad * 4 + r) * 512 + col] = acc[ng][r];
        }
    }
}

// ---- Kernel 4: reduce partials -> M (64x400), yty (64x64), colsum (64) ----
__global__ __launch_bounds__(256) void reduce_kernel(const float* __restrict__ Mpart,
                                                     float* __restrict__ M,
                                                     float* __restrict__ yty,
                                                     float* __restrict__ colsum) {
    int e = blockIdx.x * 256 + threadIdx.x;
    float s = 0.f;
#pragma unroll 8
    for (int ch = 0; ch < NCHUNK; ch++) s += Mpart[ch * PSTRIDE + e];
    int row = e >> 9, col = e & 511;
    if (col < 400) M[row * 400 + col] = s;
    else if (col < 464) yty[row * 64 + (col - 400)] = s;
    else if (col == 464) colsum[row] = s;
}

// ---- Kernel 5: Wfinal (+ fused exp_new/gfp) ----
__global__ __launch_bounds__(256) void finalize_w_kernel(const float* __restrict__ W,
                                                         const float* __restrict__ yty,
                                                         const float* __restrict__ M,
                                                         const float* __restrict__ colsum,
                                                         const float* __restrict__ exp_avg,
                                                         float* __restrict__ Wout,
                                                         float* __restrict__ expout) {
    __shared__ float gfps[OUT_CH];
    if (threadIdx.x < OUT_CH) {
        int o = threadIdx.x;
        float e = GAMMA_F * exp_avg[o] + ONE_MINUS_GAMMA * (colsum[o] / (float)NB_TILES);
        float s = e;
        for (int off = 32; off; off >>= 1) s += __shfl_down(s, off);
        s = __shfl(s, 0);
        float A = e / (s / (float)OUT_CH);
        gfps[o] = EPS_F * tanhf(-EPS_F * (A - 1.f)) + 1.f;
        if (blockIdx.x == 0) expout[o] = e;
    }
    __syncthreads();
    int idx = blockIdx.x * 256 + threadIdx.x;
    int o = idx / 400;
    int q = idx - o * 400;
    float dot = 0.f;
#pragma unroll 8
    for (int k = 0; k < OUT_CH; k++) dot = fmaf(yty[o * 64 + k], W[k * 400 + q], dot);
    float w = W[idx] + LR_OVER_NB * (M[idx] - dot);
    w = fmaxf(w, 0.f);
    float gp = gfps[o];
    float pos = (w > 0.f ? w : 0.f) * gp;
    float neg = (w < 0.f ? w : 0.f) / gp;
    Wout[idx] = pos + neg;
}

extern "C" void kernel_launch(void* const* d_in, const int* in_sizes, int n_in,
                              void* d_out, int out_size, void* d_ws, size_t ws_size,
                              hipStream_t stream) {
    const float* x = (const float*)d_in[0];
    const float* W = (const float*)d_in[1];
    const float* exp_avg = (const float*)d_in[2];
    float* out = (float*)d_out;

    float* wsf = (float*)d_ws;
    float* colsum = wsf;                        // 64
    float* M = wsf + 64;                        // 25600
    float* yty = wsf + 25664;                   // 4096 -> 29760
    float* Mpart = wsf + 29760;                 // 64*32768 floats
    // conv-side buffers overlaid on Mpart (dead until gemm writes it)
    uint16_t* xth = (uint16_t*)Mpart;           // 50304*16
    uint16_t* xtl = xth + XTROWS * 16;          // 50304*16
    uint16_t* wrh = xtl + XTROWS * 16;          // 26624
    uint16_t* wrl = wrh + 26624;                // 26624
    uint16_t* ybf = (uint16_t*)(wsf + 29760 + NCHUNK * PSTRIDE);  // 64*51200 bf16
    uint16_t* xsb = ybf + OUT_CH * KP2;                            // 5*16*52224 bf16
    uint16_t* ones = xsb + 5 * 16 * XS;                            // 51264 bf16

    float* Wout = out + OUT_CH * OUT_PLANE;
    float* expout = Wout + OUT_CH * IN_CH * KER * KER;

    xcast_kernel<<<4080, 256, 0, stream>>>(x, xsb, ybf, ones);
    prep_kernel<<<301, 256, 0, stream>>>(x, xth, xtl, W, wrh, wrl);
    conv_inhib_kernel<<<770, 256, 0, stream>>>(xth, xtl, wrh, wrl, out, ybf);
    gemm_kernel<<<512, 256, 0, stream>>>(ybf, xsb, ones, Mpart);
    reduce_kernel<<<128, 256, 0, stream>>>(Mpart, M, yty, colsum);
    finalize_w_kernel<<<100, 256, 0, stream>>>(W, yty, M, colsum, exp_avg, Wout, expout);
}